// Round 1
// baseline (79.866 us; speedup 1.0000x reference)
//
#include <hip/hip_runtime.h>
#include <cstdint>

// ---------------------------------------------------------------------------
// JAX PRNG replication. key(42) -> threefry2x32 key (0, 42).
// JAX_PARTITIONABLE=1 assumes jax_threefry_partitionable (default since
// jax 0.4.30): split is fold-like (subkey j = hash(key; 0, j)), and 32-bit
// random bits for flat index n are out0^out1 of hash(key; 0, n).
// If round fails with absmax ~0.05, flip to 0 (legacy iota/split-halves).
// ---------------------------------------------------------------------------
#define JAX_PARTITIONABLE 1

__host__ __device__ inline void threefry2x32(uint32_t k0, uint32_t k1,
                                             uint32_t x0, uint32_t x1,
                                             uint32_t& o0, uint32_t& o1) {
  const uint32_t ks2 = k0 ^ k1 ^ 0x1BD11BDAu;
  uint32_t v0 = x0 + k0, v1 = x1 + k1;
#define RL(v, r) (((v) << (r)) | ((v) >> (32 - (r))))
#define RND4(a, b, c, d)                                                       \
  v0 += v1; v1 = RL(v1, a); v1 ^= v0;                                          \
  v0 += v1; v1 = RL(v1, b); v1 ^= v0;                                          \
  v0 += v1; v1 = RL(v1, c); v1 ^= v0;                                          \
  v0 += v1; v1 = RL(v1, d); v1 ^= v0;
  RND4(13, 15, 26, 6)  v0 += k1;  v1 += ks2 + 1u;
  RND4(17, 29, 16, 24) v0 += ks2; v1 += k0 + 2u;
  RND4(13, 15, 26, 6)  v0 += k0;  v1 += k1 + 3u;
  RND4(17, 29, 16, 24) v0 += k1;  v1 += ks2 + 4u;
  RND4(13, 15, 26, 6)  v0 += ks2; v1 += k0 + 5u;
#undef RND4
#undef RL
  o0 = v0; o1 = v1;
}

#define IN_F 512
#define OUT_F 512
#define BATCH 512

// ---------------------------------------------------------------------------
// K1: mask generation. One block per output row o, one thread per input i.
// Computes p = softmax(pw[o,i,:])[1] (identical op sequence to jax.nn.softmax),
// bernoulli via threefry bits, ballot-packs choices, zero-connection fixup via
// jax.random.randint(k_fix,...) (span=512 is pow2 -> col = lower_bits % 512),
// writes float mask M[o][i] = selected ? 0 : 1e9.
// Note: since x in [0,1) and every row has >=1 selected edge, the reference
// min_i(x + mask) == min over selected i of x exactly; 1e9 kills unselected.
// ---------------------------------------------------------------------------
__global__ __launch_bounds__(512) void gen_mask_kernel(
    const float* __restrict__ pw, float* __restrict__ M,
    uint32_t kb0, uint32_t kb1, uint32_t kl0, uint32_t kl1) {
  const int o = blockIdx.x;
  const int i = threadIdx.x;

  const float2 w = ((const float2*)pw)[o * IN_F + i];
  const float mx = fmaxf(w.x, w.y);
  const float e0 = expf(w.x - mx);
  const float e1 = expf(w.y - mx);
  const float p = e1 / (e0 + e1);

  const uint32_t n = (uint32_t)(o * IN_F + i);
  uint32_t h0, h1, bits;
#if JAX_PARTITIONABLE
  threefry2x32(kb0, kb1, 0u, n, h0, h1);
  bits = h0 ^ h1;
#else
  {
    const uint32_t half = (uint32_t)(OUT_F * IN_F / 2);
    if (n < half) { threefry2x32(kb0, kb1, n, n + half, h0, h1); bits = h0; }
    else          { threefry2x32(kb0, kb1, n - half, n, h0, h1); bits = h1; }
  }
#endif
  // jax uniform [0,1): bitcast((bits>>9)|0x3f800000) - 1.0
  const float u = __uint_as_float((bits >> 9) | 0x3F800000u) - 1.0f;
  const bool c = u < p;

  __shared__ unsigned long long words[8];
  __shared__ int cnt;
  if (i == 0) cnt = 0;
  __syncthreads();
  const unsigned long long bal = __ballot(c);
  if ((i & 63) == 0) {
    words[i >> 6] = bal;
    atomicAdd(&cnt, __popcll(bal));
  }
  __syncthreads();
  if (cnt == 0 && i == 0) {
    uint32_t c0, c1, rb;
#if JAX_PARTITIONABLE
    threefry2x32(kl0, kl1, 0u, (uint32_t)o, c0, c1);
    rb = c0 ^ c1;
#else
    if (o < 256) { threefry2x32(kl0, kl1, (uint32_t)o, (uint32_t)(o + 256), c0, c1); rb = c0; }
    else         { threefry2x32(kl0, kl1, (uint32_t)(o - 256), (uint32_t)o, c0, c1); rb = c1; }
#endif
    const uint32_t col = rb & (IN_F - 1);  // randint span 512 (pow2): lower_bits % 512
    words[col >> 6] |= (1ull << (col & 63u));  // single writer between barriers
  }
  __syncthreads();
  const bool sel = (words[i >> 6] >> (i & 63)) & 1ull;
  M[o * IN_F + i] = sel ? 0.0f : 1e9f;
}

// ---------------------------------------------------------------------------
// K2: tiled min-plus. Tile = 64 b x 32 o, k-chunked by gridDim.z (2 chunks of
// 256). Block 256 threads; thread micro-tile 4b x 2o. LDS staged k-tiles of 64,
// stored [k][b] / [k][o] with pad so inner reads are aligned b128/b64 and only
// 2-way bank aliased (free per m136). VALU floor: 512^3*2 lane-ops = 3.4 us.
// ---------------------------------------------------------------------------
#define BT 64
#define OT 32
#define KT 64
#define NZ 2

__global__ __launch_bounds__(256) void minplus_kernel(
    const float* __restrict__ x, const float* __restrict__ M,
    float* __restrict__ part) {
  __shared__ __align__(16) float xs[KT][BT + 4];  // [k][b], stride 68 (==4 mod 32)
  __shared__ __align__(16) float ms[KT][OT + 4];  // [k][o], stride 36

  const int tid = threadIdx.x;
  const int tx = tid & 15;   // 4 b's each: b = 4*tx..4*tx+3
  const int ty = tid >> 4;   // 2 o's each: o = 2*ty..2*ty+1
  const int b0 = blockIdx.x * BT;
  const int o0 = blockIdx.y * OT;
  const int z = blockIdx.z;
  const int kbeg = z * (IN_F / NZ);

  float acc[4][2];
#pragma unroll
  for (int p = 0; p < 4; ++p) { acc[p][0] = 1e30f; acc[p][1] = 1e30f; }

  const int lr = tid >> 4;         // 0..15: row group for staging loads
  const int lc = (tid & 15) * 4;   // 0..60: col (k) offset, float4

  for (int kt = 0; kt < IN_F / NZ; kt += KT) {
    const int kk = kbeg + kt;
    // stage x tile: 64 rows(b) x 64 cols(k), perfectly coalesced float4 loads
#pragma unroll
    for (int j = 0; j < 4; ++j) {
      const int r = j * 16 + lr;
      const float4 v = *(const float4*)&x[(b0 + r) * IN_F + kk + lc];
      xs[lc + 0][r] = v.x; xs[lc + 1][r] = v.y;
      xs[lc + 2][r] = v.z; xs[lc + 3][r] = v.w;
    }
    // stage mask tile: 32 rows(o) x 64 cols(k)
#pragma unroll
    for (int j = 0; j < 2; ++j) {
      const int r = j * 16 + lr;
      const float4 v = *(const float4*)&M[(o0 + r) * IN_F + kk + lc];
      ms[lc + 0][r] = v.x; ms[lc + 1][r] = v.y;
      ms[lc + 2][r] = v.z; ms[lc + 3][r] = v.w;
    }
    __syncthreads();
#pragma unroll
    for (int k = 0; k < KT; ++k) {
      const float4 xv = *(const float4*)&xs[k][tx * 4];   // 16B aligned
      const float2 mv = *(const float2*)&ms[k][ty * 2];   // 8B aligned
      acc[0][0] = fminf(acc[0][0], xv.x + mv.x);
      acc[1][0] = fminf(acc[1][0], xv.y + mv.x);
      acc[2][0] = fminf(acc[2][0], xv.z + mv.x);
      acc[3][0] = fminf(acc[3][0], xv.w + mv.x);
      acc[0][1] = fminf(acc[0][1], xv.x + mv.y);
      acc[1][1] = fminf(acc[1][1], xv.y + mv.y);
      acc[2][1] = fminf(acc[2][1], xv.z + mv.y);
      acc[3][1] = fminf(acc[3][1], xv.w + mv.y);
    }
    __syncthreads();
  }

  float* pz = part + (size_t)z * (BATCH * OUT_F);
#pragma unroll
  for (int p = 0; p < 4; ++p) {
    const float2 st = make_float2(acc[p][0], acc[p][1]);
    *(float2*)&pz[(b0 + tx * 4 + p) * OUT_F + o0 + ty * 2] = st;
  }
}

// ---------------------------------------------------------------------------
// K3: fold the NZ=2 k-chunk partials into d_out.
// ---------------------------------------------------------------------------
__global__ __launch_bounds__(256) void reduce_kernel(
    const float* __restrict__ part, float* __restrict__ out) {
  const int n = blockIdx.x * 256 + threadIdx.x;  // float4 index
  const float4 a = ((const float4*)part)[n];
  const float4 b = ((const float4*)(part + BATCH * OUT_F))[n];
  ((float4*)out)[n] = make_float4(fminf(a.x, b.x), fminf(a.y, b.y),
                                  fminf(a.z, b.z), fminf(a.w, b.w));
}

extern "C" void kernel_launch(void* const* d_in, const int* in_sizes, int n_in,
                              void* d_out, int out_size, void* d_ws, size_t ws_size,
                              hipStream_t stream) {
  (void)in_sizes; (void)n_in; (void)out_size; (void)ws_size;
  const float* x = (const float*)d_in[0];        // [512, 512]
  const float* pw = (const float*)d_in[1];       // [512, 512, 2]
  float* M = (float*)d_ws;                       // 1 MB
  float* part = (float*)d_ws + BATCH * OUT_F;    // 2 MB (NZ partials)
  float* out = (float*)d_out;

  // Derive subkeys on host (pure integer math, graph-capture safe).
  uint32_t kb0, kb1, kf0, kf1, kl0, kl1;
#if JAX_PARTITIONABLE
  threefry2x32(0u, 42u, 0u, 0u, kb0, kb1);     // k_bern = hash(key; 0,0)
  threefry2x32(0u, 42u, 0u, 1u, kf0, kf1);     // k_fix  = hash(key; 0,1)
  threefry2x32(kf0, kf1, 0u, 1u, kl0, kl1);    // randint lower-bits key = hash(k_fix; 0,1)
#else
  uint32_t a0, a1, b0_, b1_, c0, c1, d0, d1;
  threefry2x32(0u, 42u, 0u, 2u, a0, a1);       // legacy split counts [0,1,2,3]
  threefry2x32(0u, 42u, 1u, 3u, b0_, b1_);
  kb0 = a0; kb1 = b0_;                          // row0 = k_bern
  kf0 = a1; kf1 = b1_;                          // row1 = k_fix
  threefry2x32(kf0, kf1, 0u, 2u, c0, c1);      // randint's internal split
  threefry2x32(kf0, kf1, 1u, 3u, d0, d1);
  kl0 = c1; kl1 = d1;                           // k2 (lower bits)
#endif

  gen_mask_kernel<<<dim3(OUT_F), dim3(IN_F), 0, stream>>>(pw, M, kb0, kb1, kl0, kl1);
  minplus_kernel<<<dim3(BATCH / BT, OUT_F / OT, NZ), dim3(256), 0, stream>>>(x, M, part);
  reduce_kernel<<<dim3(BATCH * OUT_F / 4 / 256), dim3(256), 0, stream>>>(part, out);
}

// Round 2
// 75.306 us; speedup vs baseline: 1.0605x; 1.0605x over previous
//
#include <hip/hip_runtime.h>
#include <cstdint>

// ---------------------------------------------------------------------------
// JAX PRNG replication (verified bit-exact in round 1, absmax 0.0).
// key(42) -> threefry2x32 key (0,42), jax_threefry_partitionable semantics.
// ---------------------------------------------------------------------------
__host__ __device__ inline void threefry2x32(uint32_t k0, uint32_t k1,
                                             uint32_t x0, uint32_t x1,
                                             uint32_t& o0, uint32_t& o1) {
  const uint32_t ks2 = k0 ^ k1 ^ 0x1BD11BDAu;
  uint32_t v0 = x0 + k0, v1 = x1 + k1;
#define RL(v, r) (((v) << (r)) | ((v) >> (32 - (r))))
#define RND4(a, b, c, d)                                                       \
  v0 += v1; v1 = RL(v1, a); v1 ^= v0;                                          \
  v0 += v1; v1 = RL(v1, b); v1 ^= v0;                                          \
  v0 += v1; v1 = RL(v1, c); v1 ^= v0;                                          \
  v0 += v1; v1 = RL(v1, d); v1 ^= v0;
  RND4(13, 15, 26, 6)  v0 += k1;  v1 += ks2 + 1u;
  RND4(17, 29, 16, 24) v0 += ks2; v1 += k0 + 2u;
  RND4(13, 15, 26, 6)  v0 += k0;  v1 += k1 + 3u;
  RND4(17, 29, 16, 24) v0 += k1;  v1 += ks2 + 4u;
  RND4(13, 15, 26, 6)  v0 += ks2; v1 += k0 + 5u;
#undef RND4
#undef RL
  o0 = v0; o1 = v1;
}

#define IN_F 512
#define OUT_F 512
#define BATCH 512

// ---------------------------------------------------------------------------
// K1: mask generation — UNCHANGED from round 1 (bit-exact verified).
// M[o][i] = selected ? 0 : 1e9.  Since x in [0,1) and every row has >=1
// selected edge, min_i(x+mask) == min over selected i of x, bit-exact.
// ---------------------------------------------------------------------------
__global__ __launch_bounds__(512) void gen_mask_kernel(
    const float* __restrict__ pw, float* __restrict__ M,
    uint32_t kb0, uint32_t kb1, uint32_t kl0, uint32_t kl1) {
  const int o = blockIdx.x;
  const int i = threadIdx.x;

  const float2 w = ((const float2*)pw)[o * IN_F + i];
  const float mx = fmaxf(w.x, w.y);
  const float e0 = expf(w.x - mx);
  const float e1 = expf(w.y - mx);
  const float p = e1 / (e0 + e1);

  const uint32_t n = (uint32_t)(o * IN_F + i);
  uint32_t h0, h1;
  threefry2x32(kb0, kb1, 0u, n, h0, h1);
  const uint32_t bits = h0 ^ h1;
  const float u = __uint_as_float((bits >> 9) | 0x3F800000u) - 1.0f;
  const bool c = u < p;

  __shared__ unsigned long long words[8];
  __shared__ int cnt;
  if (i == 0) cnt = 0;
  __syncthreads();
  const unsigned long long bal = __ballot(c);
  if ((i & 63) == 0) {
    words[i >> 6] = bal;
    atomicAdd(&cnt, __popcll(bal));
  }
  __syncthreads();
  if (cnt == 0 && i == 0) {
    uint32_t c0, c1;
    threefry2x32(kl0, kl1, 0u, (uint32_t)o, c0, c1);
    const uint32_t rb = c0 ^ c1;
    const uint32_t col = rb & (IN_F - 1);
    words[col >> 6] |= (1ull << (col & 63u));
  }
  __syncthreads();
  const bool sel = (words[i >> 6] >> (i & 63)) & 1ull;
  M[o * IN_F + i] = sel ? 0.0f : 1e9f;
}

// ---------------------------------------------------------------------------
// K2: min-plus, full K per block, writes d_out directly (no partials/reduce).
// Tile 32b x 16o, KT=128. Grid 16x32 = 512 blocks = 2 blocks/CU = 2 waves/SIMD
// (TLP to hide LDS latency — round-1 version had 1 wave/SIMD and stalled).
// LDS strides 33/17: staging transpose stores are 4-way aliased (1.58x, small
// volume); inner reads conflict-free/broadcast. Inner loop is at the
// 2-VALU-per-element floor: per k per thread, 2 add + 2 min for 2 outputs.
// ---------------------------------------------------------------------------
#define BT 32
#define OT 16
#define KT 128

__global__ __launch_bounds__(256) void minplus_kernel(
    const float* __restrict__ x, const float* __restrict__ M,
    float* __restrict__ out) {
  __shared__ float xs[KT][BT + 1];  // [k][b], stride 33
  __shared__ float ms[KT][OT + 1];  // [k][o], stride 17

  const int tid = threadIdx.x;
  const int tx = tid & 15;   // b pair: b = 2*tx, 2*tx+1
  const int ty = tid >> 4;   // o: o = o0 + ty  (0..15)
  const int b0 = blockIdx.x * BT;
  const int o0 = blockIdx.y * OT;

  const int sr = tid >> 5;        // 0..7: staging row group
  const int sc = (tid & 31) * 4;  // 0..124: staging k offset (float4)

  float acc0 = 1e30f, acc1 = 1e30f;

  for (int kt = 0; kt < IN_F; kt += KT) {
    // stage x tile: 32 rows(b) x 128 cols(k); coalesced float4 loads
#pragma unroll
    for (int j = 0; j < 4; ++j) {
      const int r = j * 8 + sr;
      const float4 v = *(const float4*)&x[(b0 + r) * IN_F + kt + sc];
      xs[sc + 0][r] = v.x; xs[sc + 1][r] = v.y;
      xs[sc + 2][r] = v.z; xs[sc + 3][r] = v.w;
    }
    // stage mask tile: 16 rows(o) x 128 cols(k)
#pragma unroll
    for (int j = 0; j < 2; ++j) {
      const int r = j * 8 + sr;
      const float4 v = *(const float4*)&M[(o0 + r) * IN_F + kt + sc];
      ms[sc + 0][r] = v.x; ms[sc + 1][r] = v.y;
      ms[sc + 2][r] = v.z; ms[sc + 3][r] = v.w;
    }
    __syncthreads();
#pragma unroll 16
    for (int k = 0; k < KT; ++k) {
      const float2 xv = *(const float2*)&xs[k][tx * 2];  // conflict-free b64
      const float mv = ms[k][ty];                        // 16-lane broadcast
      acc0 = fminf(acc0, xv.x + mv);
      acc1 = fminf(acc1, xv.y + mv);
    }
    __syncthreads();
  }

  out[(b0 + tx * 2 + 0) * OUT_F + o0 + ty] = acc0;
  out[(b0 + tx * 2 + 1) * OUT_F + o0 + ty] = acc1;
}

extern "C" void kernel_launch(void* const* d_in, const int* in_sizes, int n_in,
                              void* d_out, int out_size, void* d_ws, size_t ws_size,
                              hipStream_t stream) {
  (void)in_sizes; (void)n_in; (void)out_size; (void)ws_size;
  const float* x = (const float*)d_in[0];   // [512, 512]
  const float* pw = (const float*)d_in[1];  // [512, 512, 2]
  float* M = (float*)d_ws;                  // 1 MB
  float* out = (float*)d_out;

  uint32_t kb0, kb1, kf0, kf1, kl0, kl1;
  threefry2x32(0u, 42u, 0u, 0u, kb0, kb1);   // k_bern = hash(key; 0,0)
  threefry2x32(0u, 42u, 0u, 1u, kf0, kf1);   // k_fix  = hash(key; 0,1)
  threefry2x32(kf0, kf1, 0u, 1u, kl0, kl1);  // randint lower-bits key

  gen_mask_kernel<<<dim3(OUT_F), dim3(IN_F), 0, stream>>>(pw, M, kb0, kb1, kl0, kl1);
  minplus_kernel<<<dim3(BATCH / BT, OUT_F / OT), dim3(256), 0, stream>>>(x, M, out);
}